// Round 6
// baseline (106.582 us; speedup 1.0000x reference)
//
#include <hip/hip_runtime.h>
#include <math.h>

#define NBINS  128
#define DFINE  2272        // fine-grid cells (1/16 bin): d = floor(16*t)+DOFF, taps within [0,2268]
#define DOFF   118
#define GT_N   235         // g-table: G[m] = g((m-117)/16); g==0 beyond |u|~7.3 in f32
#define NB     512         // 2 blocks/CU, 8 waves/CU
#define REP    4           // bank-partitioned replicas: D[c*4 + (lane&3)] -> bank%4 == lane&3,
                           // so the 4 lane-classes NEVER share a bank on the scatter ds_adds
#define DPAD   2414        // DFINE + DFINE/16, +1-per-16 padded conv buffer (bank-conflict-free)

// Clear the single global fine-grid accumulator (harness poisons ws between runs).
__global__ __launch_bounds__(256) void zero_kernel(float* __restrict__ Dt) {
    int i = blockIdx.x * 256 + threadIdx.x;
    if (i < DFINE) Dt[i] = 0.0f;
}

// Scatter: hist[j] = sum_i g(j - t_i), g(u) = ndtr(u+1) - ndtr(u)  (bandwidth == resolution).
// Each point deposits its 4 Catmull-Rom weights onto a 1/16-bin fine grid in LDS via
// native ds_add_f32. The grid is replicated 4x, interleaved by lane&3, so scatter
// atomics from different lane-classes are bank-disjoint (the round-5 bottleneck was
// ~5-way random bank collisions on the atomic RMW path, ~25+ cy/point).
__global__ __launch_bounds__(256) void hist_kernel(const float* __restrict__ x,
                                                   const float* __restrict__ edges,
                                                   float* __restrict__ Dt, int n) {
    __shared__ float D[DFINE * REP];
    for (int i = threadIdx.x; i < DFINE * REP; i += 256) D[i] = 0.0f;
    __syncthreads();

    const float e0 = edges[0];
    const float res = edges[1] - e0;
    const float sc = 16.0f / res;                    // t16 = 16 * (x - e0)/res
    const int l4 = threadIdx.x & 3;                  // bank-class of this lane

    const int nth = NB * 256;
    for (int base = (blockIdx.x * 256 + threadIdx.x) * 4; base < n; base += nth * 4) {
        float xs[4];
        #pragma unroll
        for (int k = 0; k < 4; ++k) {                // 4 consecutive points: dense reads, 4-deep MLP
            int idx = base + k;
            xs[k] = (idx < n) ? x[(size_t)idx * 6] : -1.0e9f;   // AXIS=0 of row-major (N,6)
        }
        #pragma unroll
        for (int k = 0; k < 4; ++k) {
            float t16 = (xs[k] - e0) * sc;
            float fq = floorf(t16);
            int qf = (int)fq;
            if (qf < -117 || qf > 2148) continue;    // contributes exactly 0 to every bin in f32
            float s = t16 - fq;
            float s2 = s * s, s3 = s2 * s;
            float w0 = fmaf(-0.5f, s3, s2) - 0.5f * s;
            float w1 = fmaf(1.5f, s3, fmaf(-2.5f, s2, 1.0f));
            float w2 = fmaf(-1.5f, s3, fmaf(2.0f, s2, 0.5f * s));
            float w3 = fmaf(0.5f, s3, -0.5f * s2);   // w0+w1+w2+w3 == 1 exactly
            int b = (qf + DOFF - 1) * REP + l4;      // cell q-1, this lane's replica
            unsafeAtomicAdd(&D[b],           w0);    // native ds_add_f32, bank-disjoint classes
            unsafeAtomicAdd(&D[b + REP],     w1);
            unsafeAtomicAdd(&D[b + 2 * REP], w2);
            unsafeAtomicAdd(&D[b + 3 * REP], w3);
        }
    }
    __syncthreads();
    for (int i = threadIdx.x; i < DFINE; i += 256) { // fold replicas, atomic flush, skip empties
        int b = i * REP;
        float v = (D[b] + D[b + 1]) + (D[b + 2] + D[b + 3]);
        if (v != 0.0f) unsafeAtomicAdd(&Dt[i], v);   // native global_atomic_add_f32 (no return)
    }
}

// Convolution + normalization in one 128-thread block. Builds the erf table here (once).
__global__ __launch_bounds__(128) void final_kernel(const float* __restrict__ Dt,
                                                    const float* __restrict__ edges,
                                                    float* __restrict__ out) {
    __shared__ float G[GT_N];
    __shared__ float Ds[DPAD];
    __shared__ float hs[NBINS];
    const int t = threadIdx.x;                       // exactly 128 threads, thread t = bin t
    const float inv_sqrt2 = 0.70710678118654752440f;
    for (int k = t; k < GT_N; k += 128) {
        float u = (float)(k - 117) * 0.0625f;
        G[k] = 0.5f * (erff((u + 1.0f) * inv_sqrt2) - erff(u * inv_sqrt2));
    }
    for (int dd = t; dd < DFINE; dd += 128)
        Ds[dd + (dd >> 4)] = Dt[dd];                 // +1/16 pad: conv reads hit distinct banks
    __syncthreads();

    float acc = 0.0f;
    const int p0 = 16 * t;
    #pragma unroll 5
    for (int r = 1; r <= GT_N; ++r) {                // hist[t] = sum_r D[16t+r] * g-table[235-r]
        int idx = p0 + r;
        acc = fmaf(Ds[idx + (idx >> 4)], G[GT_N - r], acc);
    }
    hs[t] = acc;
    __syncthreads();
    for (int off = NBINS / 2; off >= 1; off >>= 1) {
        if (t < off) hs[t] += hs[t + off];
        __syncthreads();
    }
    float res = edges[1] - edges[0];
    out[t] = acc / (hs[0] * res);                    // mean factor 1/n cancels in normalization
}

extern "C" void kernel_launch(void* const* d_in, const int* in_sizes, int n_in,
                              void* d_out, int out_size, void* d_ws, size_t ws_size,
                              hipStream_t stream) {
    const float* x     = (const float*)d_in[0];
    const float* edges = (const float*)d_in[1];
    float* out = (float*)d_out;
    float* Dt  = (float*)d_ws;                       // 2272 floats of workspace used
    int n = in_sizes[0] / 6;

    zero_kernel<<<(DFINE + 255) / 256, 256, 0, stream>>>(Dt);
    hist_kernel<<<NB, 256, 0, stream>>>(x, edges, Dt, n);
    final_kernel<<<1, 128, 0, stream>>>(Dt, edges, out);
}